// Round 8
// baseline (197.841 us; speedup 1.0000x reference)
//
#include <hip/hip_runtime.h>
#include <cmath>

#define B_ 16384
#define S_ 512
#define P_ 1024
#define K_ 8
#define D_ 64
#define H_ 128

typedef float f32x2 __attribute__((ext_vector_type(2)));
typedef float f32x4 __attribute__((ext_vector_type(4)));
typedef _Float16 half8 __attribute__((ext_vector_type(8)));

// ---------------- Kernel A: sklproj[s][h] = dot(skl_emd[s,:], U[h,:]) ----------------
__global__ __launch_bounds__(128) void proj_skl_kernel(
    const float* __restrict__ skl_emd, const float* __restrict__ U,
    float* __restrict__ sklproj) {
  __shared__ float row[D_];
  const int s = blockIdx.x, h = threadIdx.x;
  if (h < D_) row[h] = skl_emd[s * D_ + h];
  __syncthreads();
  const float4* __restrict__ Urow = (const float4*)(U + (size_t)h * D_);
  float acc = 0.f;
#pragma unroll
  for (int i = 0; i < D_ / 4; i++) {
    const float4 u = Urow[i];
    acc += row[4 * i] * u.x;
    acc += row[4 * i + 1] * u.y;
    acc += row[4 * i + 2] * u.z;
    acc += row[4 * i + 3] * u.w;
  }
  sklproj[s * H_ + h] = acc;
}

// ---------------- Kernel B: att[p][k] = softmax_k( sum_h v[h]*tanh(projP[p][h]+sklproj[g[p][k]][h]) )
__global__ __launch_bounds__(128) void att_kernel(
    const float* __restrict__ plm_emd, const float* __restrict__ W,
    const float* __restrict__ vT, const float* __restrict__ sklproj,
    const int* __restrict__ gidx, float* __restrict__ att) {
  __shared__ float prow[D_];
  __shared__ float red[2][K_];
  const int p = blockIdx.x, h = threadIdx.x;
  if (h < D_) prow[h] = plm_emd[p * D_ + h];
  __syncthreads();
  const float4* __restrict__ Wrow = (const float4*)(W + (size_t)h * D_);
  float pp = 0.f;
#pragma unroll
  for (int i = 0; i < D_ / 4; i++) {
    const float4 w = Wrow[i];
    pp += prow[4 * i] * w.x;
    pp += prow[4 * i + 1] * w.y;
    pp += prow[4 * i + 2] * w.z;
    pp += prow[4 * i + 3] * w.w;
  }
  const float v = vT[h];
  int g[K_];
#pragma unroll
  for (int k = 0; k < K_; k++) g[k] = gidx[p * K_ + k];
  float partial[K_];
#pragma unroll
  for (int k = 0; k < K_; k++) partial[k] = v * tanhf(pp + sklproj[g[k] * H_ + h]);
#pragma unroll
  for (int off = 32; off >= 1; off >>= 1)
#pragma unroll
    for (int k = 0; k < K_; k++) partial[k] += __shfl_down(partial[k], off, 64);
  const int wave = h >> 6, lane = h & 63;
  if (lane == 0)
#pragma unroll
    for (int k = 0; k < K_; k++) red[wave][k] = partial[k];
  __syncthreads();
  if (h == 0) {
    float s[K_], m = -1e30f;
#pragma unroll
    for (int k = 0; k < K_; k++) { s[k] = red[0][k] + red[1][k]; m = fmaxf(m, s[k]); }
    float denom = 0.f;
#pragma unroll
    for (int k = 0; k < K_; k++) { s[k] = expf(s[k] - m); denom += s[k]; }
    const float inv = 1.f / denom;
#pragma unroll
    for (int k = 0; k < K_; k++) att[p * K_ + k] = s[k] * inv;
  }
}

// ---------------- AT build: AT[p][s] = sum_k att[p][k] * [g[p][k]==s], fp16 ----------------
__global__ __launch_bounds__(256) void zero_AT_kernel(_Float16* __restrict__ AT) {
  const int i = blockIdx.x * 256 + threadIdx.x;  // 65536 threads x 16B = 1 MB
  ((uint4*)AT)[i] = make_uint4(0u, 0u, 0u, 0u);
}

__global__ __launch_bounds__(256) void build_AT_kernel(
    const float* __restrict__ att, const int* __restrict__ gidx,
    _Float16* __restrict__ AT) {
  const int p = blockIdx.x * 256 + threadIdx.x;  // 1024 threads, one row each
  const float4* ap = (const float4*)(att + (size_t)p * K_);
  const int4* gp = (const int4*)(gidx + (size_t)p * K_);
  const float4 a0 = ap[0], a1 = ap[1];
  const int4 g0 = gp[0], g1 = gp[1];
  float a[K_] = {a0.x, a0.y, a0.z, a0.w, a1.x, a1.y, a1.z, a1.w};
  int g[K_] = {g0.x, g0.y, g0.z, g0.w, g1.x, g1.y, g1.z, g1.w};
  // merge duplicate skill indices in f32 (each (s,p) cell written once)
#pragma unroll
  for (int k = 1; k < K_; k++)
#pragma unroll
    for (int j = 0; j < K_; j++) {
      if (j >= k) break;
      if (g[j] == g[k]) { a[j] += a[k]; g[k] = -1; break; }
    }
#pragma unroll
  for (int k = 0; k < K_; k++)
    if (g[k] >= 0) AT[(size_t)p * S_ + g[k]] = (_Float16)a[k];
}

// ---------------- GEMM: out[b][p] = mask[b][p] * sum_s pfc[b][s] * AT[p][s] ----------------
// R8: replace the latency-bound LDS-gather kernel (stuck at 43+-4 us across 6
// scheduling variants, no pipe >35%) with a dense fp16 MFMA GEMM.
// M=16384 N=1024 K=512, 17.2 GFLOP; compulsory traffic 160 MB -> ~25 us floor.
// 128x128 tile, 4 waves (2x2) of 64x64, BK=64 (8 staging rounds), fp16
// fragments per m89-verified layout. Dispatch mapping keeps all 8 N-tiles of
// an M-panel on one XCD (round-robin assumption) so pfc panels are read from
// HBM once. LDS pad 72 halves/row -> 2-way-free bank pattern on ds_read_b128.
__global__ __launch_bounds__(256) void gemm_kernel(
    const float* __restrict__ pfc, const float* __restrict__ mask,
    const _Float16* __restrict__ AT, float* __restrict__ out) {
  __shared__ _Float16 pA[128][72];  // [b-row][s] fp16, 18.4 KB
  __shared__ _Float16 pB[128][72];  // [p-row][s] fp16, 18.4 KB
  const int t = threadIdx.x;
  const int d = blockIdx.x;                 // 1024 blocks
  const int xx = d & 7, yy = d >> 3;
  const int mq = xx + 8 * (yy >> 3);        // m panel 0..127 (xcd-grouped)
  const int nj = yy & 7;                    // n panel 0..7
  const int b0 = mq * 128, p0 = nj * 128;
  const int l = t & 63, wid = t >> 6;
  const int wm = (wid >> 1) * 64, wn = (wid & 1) * 64;
  const int lr = l & 15, lq = l >> 4;

  f32x4 acc[4][4];
#pragma unroll
  for (int i = 0; i < 4; i++)
#pragma unroll
    for (int j = 0; j < 4; j++) acc[i][j] = (f32x4){0.f, 0.f, 0.f, 0.f};

  for (int step = 0; step < 8; ++step) {
    const int s0 = step * 64;
    __syncthreads();  // previous compute done before overwriting LDS
    {  // stage pfc tile [128][64] f32 -> f16; 4 thr/row, 2 row-passes
      const int r = t >> 2, c16 = (t & 3) * 16;
#pragma unroll
      for (int pass = 0; pass < 2; ++pass) {
        const int row = r + 64 * pass;
        const float4* src = (const float4*)&pfc[(size_t)(b0 + row) * S_ + s0 + c16];
        const float4 v0 = src[0], v1 = src[1], v2 = src[2], v3 = src[3];
        half8 h0, h1;
        h0[0] = (_Float16)v0.x; h0[1] = (_Float16)v0.y; h0[2] = (_Float16)v0.z; h0[3] = (_Float16)v0.w;
        h0[4] = (_Float16)v1.x; h0[5] = (_Float16)v1.y; h0[6] = (_Float16)v1.z; h0[7] = (_Float16)v1.w;
        h1[0] = (_Float16)v2.x; h1[1] = (_Float16)v2.y; h1[2] = (_Float16)v2.z; h1[3] = (_Float16)v2.w;
        h1[4] = (_Float16)v3.x; h1[5] = (_Float16)v3.y; h1[6] = (_Float16)v3.z; h1[7] = (_Float16)v3.w;
        *(half8*)&pA[row][c16] = h0;
        *(half8*)&pA[row][c16 + 8] = h1;
      }
    }
    {  // stage AT tile [128][64] f16 (already packed); 2 thr/row
      const int pr = t >> 1, c32 = (t & 1) * 32;
      const uint4* src = (const uint4*)&AT[(size_t)(p0 + pr) * S_ + s0 + c32];
#pragma unroll
      for (int i = 0; i < 4; ++i) *(uint4*)&pB[pr][c32 + 8 * i] = src[i];
    }
    __syncthreads();
#pragma unroll
    for (int kk = 0; kk < 64; kk += 32) {
      half8 aF[4], bF[4];
#pragma unroll
      for (int fm = 0; fm < 4; ++fm)
        aF[fm] = *(const half8*)&pA[wm + fm * 16 + lr][kk + lq * 8];
#pragma unroll
      for (int fn = 0; fn < 4; ++fn)
        bF[fn] = *(const half8*)&pB[wn + fn * 16 + lr][kk + lq * 8];
#pragma unroll
      for (int fm = 0; fm < 4; ++fm)
#pragma unroll
        for (int fn = 0; fn < 4; ++fn)
          acc[fm][fn] = __builtin_amdgcn_mfma_f32_16x16x32_f16(
              aF[fm], bF[fn], acc[fm][fn], 0, 0, 0);
    }
  }

  // epilogue: D layout col=l&15, row=4*(l>>4)+reg (m89-verified)
#pragma unroll
  for (int fm = 0; fm < 4; ++fm) {
#pragma unroll
    for (int j = 0; j < 4; ++j) {
      const int row = b0 + wm + fm * 16 + lq * 4 + j;
#pragma unroll
      for (int fn = 0; fn < 4; ++fn) {
        const int col = p0 + wn + fn * 16 + lr;
        const size_t idx = (size_t)row * P_ + col;
        out[idx] = acc[fm][fn][j] * mask[idx];
      }
    }
  }
}

extern "C" void kernel_launch(void* const* d_in, const int* in_sizes, int n_in,
                              void* d_out, int out_size, void* d_ws, size_t ws_size,
                              hipStream_t stream) {
  const float* skl_pfc = (const float*)d_in[0];   // [B, S]
  const float* mask    = (const float*)d_in[1];   // [B, P]
  const float* skl_emd = (const float*)d_in[2];   // [S, D]
  const float* plm_emd = (const float*)d_in[3];   // [P, D]
  const float* W       = (const float*)d_in[4];   // [H, D]
  const float* U       = (const float*)d_in[5];   // [H, D]
  const float* vT      = (const float*)d_in[6];   // [1, H]
  const int*   gidx    = (const int*)d_in[7];     // [P, K]
  float* out = (float*)d_out;                     // [B, P]

  float* sklproj = (float*)d_ws;                  // S*H floats = 256 KB
  float* att     = sklproj + S_ * H_;             // P*K floats = 32 KB
  _Float16* AT   = (_Float16*)(att + P_ * K_);    // P*S fp16  = 1 MB

  proj_skl_kernel<<<S_, 128, 0, stream>>>(skl_emd, U, sklproj);
  att_kernel<<<P_, 128, 0, stream>>>(plm_emd, W, vT, sklproj, gidx, att);
  zero_AT_kernel<<<256, 256, 0, stream>>>(AT);
  build_AT_kernel<<<P_ / 256, 256, 0, stream>>>(att, gidx, AT);
  gemm_kernel<<<1024, 256, 0, stream>>>(skl_pfc, mask, AT, out);
}